// Round 1
// 314.400 us; speedup vs baseline: 1.0036x; 1.0036x over previous
//
#include <hip/hip_runtime.h>
#include <stdint.h>

#define CNT 8
#define L1D 3072
#define NB 16384
#define BM 32
#define BN 128
#define BK 64
#define KITERS (L1D / BK)   // 48
#define LSTR 72             // bf16 elems per LDS row (64 + 8 pad): frag reads conflict-free

typedef float  float4v  __attribute__((ext_vector_type(4)));
typedef short  short8   __attribute__((ext_vector_type(8)));
typedef unsigned short ushort4v __attribute__((ext_vector_type(4)));

__device__ __forceinline__ unsigned short f2bf(float f) {
  uint32_t u = __builtin_bit_cast(uint32_t, f);
  u += 0x7fffu + ((u >> 16) & 1u);   // RNE; inputs are finite
  return (unsigned short)(u >> 16);
}

// Build combined weights: W'[b*16+j][k] = l1_w[b*16+j][k] + l1f_w[j][k]  (bf16)
//                         b'[b*16+j]    = l1_b[b*16+j]    + l1f_b[j]     (fp32)
__global__ void prep_kernel(const float* __restrict__ l1w, const float* __restrict__ l1b,
                            const float* __restrict__ l1fw, const float* __restrict__ l1fb,
                            unsigned short* __restrict__ cw, float* __restrict__ cb) {
  const int n = blockIdx.y;                       // 0..127
  const int k = blockIdx.x * 256 + threadIdx.x;   // 0..3071
  cw[n * L1D + k] = f2bf(l1w[n * L1D + k] + l1fw[(n & 15) * L1D + k]);
  if (blockIdx.x == 0 && n == 0 && threadIdx.x < 128)
    cb[threadIdx.x] = l1b[threadIdx.x] + l1fb[threadIdx.x & 15];
}

union __align__(16) SMem {
  struct {
    unsigned short A[2][BM * LSTR];   // 9216 B
    unsigned short B[2][BN * LSTR];   // 36864 B
  } st;                               // 46080 B total -> 2 blocks/CU fit in 160 KiB
  struct {
    float yg[BM][20];                 // gathered per-row y (16 used, pad 20)
    float l2w[960 * 9];               // [(n*30+k)*9 + b]
    float outw[256];                  // [n*8+b]
    float l2b[256];                   // [b*32+n]
    float bias[128];                  // combined l1 bias
    int   buck[BM];
  } ep;                               // 39808 B
};

// BM=32: grid = 512 blocks = 2 blocks/CU -> inter-block overlap hides load
// latency + barrier drain (single resident block had 1 wave/SIMD, no hiding).
__global__ __launch_bounds__(256, 2) void fused_kernel(
    const float* __restrict__ x, const int* __restrict__ lsi,
    const unsigned short* __restrict__ cw, const float* __restrict__ cb,
    const float* __restrict__ gl2w, const float* __restrict__ gl2b,
    const float* __restrict__ goutw, const float* __restrict__ goutb,
    float* __restrict__ out) {
  __shared__ SMem sm;
  const int tid  = threadIdx.x;
  const int lane = tid & 63;
  const int wid  = tid >> 6;
  const int rowbase = blockIdx.x * BM;

  // staging maps: A: 2 passes of (row = p*16 + tid>>4, float4 = tid&15) -> coalesced 256B/row
  const int ar = tid >> 4, af = tid & 15;
  // B: 4 passes of (row = p*32 + tid>>3, 8-bf16 chunk = tid&7) -> coalesced 128B/row
  const int br = tid >> 3, bc = tid & 7;
  const float* xp = x + (size_t)(rowbase + ar) * L1D + af * 4;
  const unsigned short* wp = cw + (size_t)br * L1D + bc * 8;

  float4v aR[2];
  short8  bR[4];
  // wave covers both m-tiles x 2 n-tiles (nt = wid*2 + j)
  float4v acc[2][2];
#pragma unroll
  for (int i = 0; i < 2; ++i)
#pragma unroll
    for (int j = 0; j < 2; ++j) acc[i][j] = float4v{0.f, 0.f, 0.f, 0.f};

  // prologue: tile 0 -> regs -> LDS[0]
#pragma unroll
  for (int p = 0; p < 2; ++p) aR[p] = *(const float4v*)(xp + (size_t)p * 16 * L1D);
#pragma unroll
  for (int p = 0; p < 4; ++p) bR[p] = *(const short8*)(wp + (size_t)p * 32 * L1D);
#pragma unroll
  for (int p = 0; p < 2; ++p) {
    ushort4v v = {f2bf(aR[p].x), f2bf(aR[p].y), f2bf(aR[p].z), f2bf(aR[p].w)};
    *(ushort4v*)&sm.st.A[0][(p * 16 + ar) * LSTR + af * 4] = v;
  }
#pragma unroll
  for (int p = 0; p < 4; ++p)
    *(short8*)&sm.st.B[0][(p * 32 + br) * LSTR + bc * 8] = bR[p];
  __syncthreads();

  for (int it = 0; it < KITERS; ++it) {
    const int buf = it & 1;
    if (it + 1 < KITERS) {               // prefetch next tile into regs (overlaps MFMA)
      const int koff = (it + 1) * BK;
#pragma unroll
      for (int p = 0; p < 2; ++p) aR[p] = *(const float4v*)(xp + (size_t)p * 16 * L1D + koff);
#pragma unroll
      for (int p = 0; p < 4; ++p) bR[p] = *(const short8*)(wp + (size_t)p * 32 * L1D + koff);
    }
#pragma unroll
    for (int ks = 0; ks < 2; ++ks) {
      const int kk = ks * 32 + (lane >> 4) * 8;
      short8 afr[2], bfr[2];
#pragma unroll
      for (int i = 0; i < 2; ++i)
        afr[i] = *(const short8*)&sm.st.A[buf][(i * 16 + (lane & 15)) * LSTR + kk];
#pragma unroll
      for (int j = 0; j < 2; ++j)
        bfr[j] = *(const short8*)&sm.st.B[buf][((wid * 2 + j) * 16 + (lane & 15)) * LSTR + kk];
#pragma unroll
      for (int i = 0; i < 2; ++i)
#pragma unroll
        for (int j = 0; j < 2; ++j)
          acc[i][j] = __builtin_amdgcn_mfma_f32_16x16x32_bf16(afr[i], bfr[j], acc[i][j], 0, 0, 0);
    }
    if (it + 1 < KITERS) {
#pragma unroll
      for (int p = 0; p < 2; ++p) {
        ushort4v v = {f2bf(aR[p].x), f2bf(aR[p].y), f2bf(aR[p].z), f2bf(aR[p].w)};
        *(ushort4v*)&sm.st.A[buf ^ 1][(p * 16 + ar) * LSTR + af * 4] = v;
      }
#pragma unroll
      for (int p = 0; p < 4; ++p)
        *(short8*)&sm.st.B[buf ^ 1][(p * 32 + br) * LSTR + bc * 8] = bR[p];
      __syncthreads();
    }
  }
  __syncthreads();   // staging LDS dead; epilogue view begins

  // stage epilogue tables into (aliased) LDS
  if (tid < BM)  sm.ep.buck[tid] = lsi[rowbase + tid];
  if (tid < 128) sm.ep.bias[tid] = cb[tid];
  {
    const int b2 = tid >> 5, n2 = tid & 31;
    sm.ep.outw[n2 * 8 + b2] = goutw[tid];   // out_w[b][n] -> [n*8+b]
    sm.ep.l2b[tid] = gl2b[tid];
  }
  for (int i = tid; i < 960 * 8; i += 256) {
    const int b = i / 960;
    const int rem = i - b * 960;            // = n*30+k
    sm.ep.l2w[rem * 9 + b] = gl2w[i];
  }
  __syncthreads();

  // scatter accumulators: row r needs n-tile == bucket[r] (16-aligned gather)
#pragma unroll
  for (int i = 0; i < 2; ++i)
#pragma unroll
    for (int j = 0; j < 2; ++j) {
      const int nt = wid * 2 + j;
#pragma unroll
      for (int rg = 0; rg < 4; ++rg) {
        const int r = i * 16 + (lane >> 4) * 4 + rg;  // C/D: col=lane&15, row=quad*4+reg
        if (sm.ep.buck[r] == nt) sm.ep.yg[r][lane & 15] = acc[i][j][rg];
      }
    }
  __syncthreads();

  // tail network: 8 threads per row, 4 l2-neurons each, shuffle-reduce (width 8)
  {
    const int r = tid >> 3, q = tid & 7;
    const int b = sm.ep.buck[r];
    float act[30];
#pragma unroll
    for (int c = 0; c < 15; ++c) {
      const float v = sm.ep.yg[r][c] + sm.ep.bias[b * 16 + c];
      act[c]      = fminf(v * v * (127.0f / 128.0f), 1.0f);   // square part (>=0, clip hi only)
      act[15 + c] = fminf(fmaxf(v, 0.0f), 1.0f);              // linear part
    }
    const float y15 = sm.ep.yg[r][15] + sm.ep.bias[b * 16 + 15];  // l1c_out + l1f_out
    float o = 0.0f;
#pragma unroll
    for (int nn = 0; nn < 4; ++nn) {
      const int n = q * 4 + nn;
      float s = sm.ep.l2b[b * 32 + n];
#pragma unroll
      for (int k = 0; k < 30; ++k) s += act[k] * sm.ep.l2w[(n * 30 + k) * 9 + b];
      s = fminf(fmaxf(s, 0.0f), 1.0f);
      o += s * sm.ep.outw[n * 8 + b];
    }
    o += __shfl_down(o, 4, 8);
    o += __shfl_down(o, 2, 8);
    o += __shfl_down(o, 1, 8);
    if (q == 0) out[rowbase + r] = o + y15 + goutb[b];
  }
}

extern "C" void kernel_launch(void* const* d_in, const int* in_sizes, int n_in,
                              void* d_out, int out_size, void* d_ws, size_t ws_size,
                              hipStream_t stream) {
  const float* x    = (const float*)d_in[0];
  const int*   lsi  = (const int*)d_in[1];
  const float* l1w  = (const float*)d_in[2];
  const float* l1b  = (const float*)d_in[3];
  const float* l1fw = (const float*)d_in[4];
  const float* l1fb = (const float*)d_in[5];
  const float* l2w  = (const float*)d_in[6];
  const float* l2b  = (const float*)d_in[7];
  const float* outw = (const float*)d_in[8];
  const float* outb = (const float*)d_in[9];
  float* out = (float*)d_out;

  unsigned short* cw = (unsigned short*)d_ws;                    // 128*3072 bf16 = 786432 B
  float* cb = (float*)((char*)d_ws + 128 * L1D * sizeof(unsigned short)); // +512 B

  prep_kernel<<<dim3(12, 128), 256, 0, stream>>>(l1w, l1b, l1fw, l1fb, cw, cb);
  fused_kernel<<<NB / BM, 256, 0, stream>>>(x, lsi, cw, cb, l2w, l2b, outw, outb, out);
}